// Round 9
// baseline (620.226 us; speedup 1.0000x reference)
//
#include <hip/hip_runtime.h>
#include <math.h>

#define NOBS 1024
#define NX   128
#define NY   256
#define NIT  200
#define ROWS 2                      // rows per FISTA block
#define NBLK (NOBS / ROWS)          // 512 blocks -> 2 blocks/CU co-resident

typedef _Float16 f16x8 __attribute__((ext_vector_type(8)));
typedef _Float16 f16x4 __attribute__((ext_vector_type(4)));
typedef float    f32x4 __attribute__((ext_vector_type(4)));

// ---- fast 64-lane sum: 6 DPP adds, total lands in lane 63, readlane -> SGPR
template <int CTRL>
__device__ __forceinline__ float dpp_add(float x) {
    int yi = __builtin_amdgcn_update_dpp(0, __builtin_bit_cast(int, x),
                                         CTRL, 0xF, 0xF, true);
    return x + __builtin_bit_cast(float, yi);
}
__device__ __forceinline__ float dpp_sum64(float x) {
    x = dpp_add<0x111>(x);   // row_shr:1
    x = dpp_add<0x112>(x);   // row_shr:2
    x = dpp_add<0x114>(x);   // row_shr:4
    x = dpp_add<0x118>(x);   // row_shr:8
    x = dpp_add<0x142>(x);   // row_bcast:15
    x = dpp_add<0x143>(x);   // row_bcast:31
    return __builtin_bit_cast(float,
        __builtin_amdgcn_readlane(__builtin_bit_cast(int, x), 63));
}

// ---------------------------------------------------------------------------
// K1: Y_hat = X @ W^T + b      grid=(NOBS), block=256 (thread j -> column j)
// ---------------------------------------------------------------------------
__global__ __launch_bounds__(256) void yhat_kernel(const float* __restrict__ X,
                                                   const float* __restrict__ W,
                                                   const float* __restrict__ b,
                                                   float* __restrict__ yhat) {
    __shared__ float xs[NX];
    const int i = blockIdx.x;
    const int j = threadIdx.x;
    if (j < NX) xs[j] = X[i * NX + j];
    __syncthreads();
    const float4* wr = reinterpret_cast<const float4*>(W + j * NX);
    const float4* xr = reinterpret_cast<const float4*>(xs);
    float acc = b[j];
#pragma unroll
    for (int k = 0; k < NX / 4; ++k) {
        float4 w4 = wr[k];
        float4 x4 = xr[k];
        acc += w4.x * x4.x + w4.y * x4.y + w4.z * x4.z + w4.w * x4.w;
    }
    yhat[i * NY + j] = acc;
}

// ---------------------------------------------------------------------------
// K2: M[a][j] = (1/N) sum_i ep[i][a]*ep[i][j]; cs[a] = column sums of ep
// ---------------------------------------------------------------------------
__global__ __launch_bounds__(256) void sigmaM_kernel(const float* __restrict__ Y,
                                                     const float* __restrict__ yhat,
                                                     float* __restrict__ M,
                                                     float* __restrict__ cs) {
    const int a = blockIdx.x;
    const int j = threadIdx.x;
    __shared__ float ca[NOBS];
    for (int i = j; i < NOBS; i += 256)
        ca[i] = Y[i * NY + a] - yhat[i * NY + a];
    __syncthreads();
    float s4 = ca[j] + ca[j + 256] + ca[j + 512] + ca[j + 768];
    float wsum = dpp_sum64(s4);
    __shared__ float red[4];
    if ((j & 63) == 0) red[j >> 6] = wsum;
    __syncthreads();
    if (j == 0) cs[a] = red[0] + red[1] + red[2] + red[3];
    float s = 0.f;
#pragma unroll 4
    for (int i = 0; i < NOBS; ++i) {
        float cj = Y[i * NY + j] - yhat[i * NY + j];
        s += ca[i] * cj;
    }
    M[a * NY + j] = s * (1.0f / NOBS);
}

// ---------------------------------------------------------------------------
// K3: step = 1 / (2*||M - mu mu'||_F + 1e-8)      grid=(1), block=1024
// ---------------------------------------------------------------------------
__global__ __launch_bounds__(1024) void step_kernel(const float* __restrict__ M,
                                                    const float* __restrict__ cs,
                                                    float* __restrict__ stepv) {
    const int t = threadIdx.x;
    const float invN2 = 1.0f / ((float)NOBS * (float)NOBS);
    float s = 0.f;
    for (int idx = t; idx < NY * NY; idx += 1024) {
        const int a = idx >> 8, j = idx & 255;
        float v = M[idx] - cs[a] * cs[j] * invN2;
        s += v * v;
    }
#pragma unroll
    for (int off = 32; off; off >>= 1) s += __shfl_xor(s, off);
    __shared__ float red[16];
    if ((t & 63) == 0) red[t >> 6] = s;
    __syncthreads();
    if (t < 16) {
        float v = red[t];
#pragma unroll
        for (int off = 8; off; off >>= 1) v += __shfl_xor(v, off);
        if (t == 0) stepv[0] = 1.0f / (2.0f * sqrtf(v) + 1e-8f);
    }
}

// ---------------------------------------------------------------------------
// K4 template: r7-structure FISTA with ablation variants (instrumentation).
// VARIANT 0: full r7.  1: single Newton trip.  2: no cross-wave exchange
// (no dump/BAR1/g-read; g from own acc regs).  NEWTCAP: mid-stream trip cap.
// Variant dispatches (NITER=50) write into the z region of d_out; the final
// VARIANT-0/NITER-200 dispatch overwrites every byte deterministically.
// ---------------------------------------------------------------------------
template <int NITER, int VARIANT, int NEWTCAP>
__global__ __launch_bounds__(256, 2) void fista_t(
        const float* __restrict__ M,
        const float* __restrict__ cs,
        const float* __restrict__ yhat,
        const float* __restrict__ stepv,
        float* __restrict__ zout) {
    __shared__ _Float16 zyA[16 * 256];   // A matrix, swizzled: byte ^= (row&7)<<4
    __shared__ float    gbuf[ROWS * 256]; // raw grad exchange

    const int tid  = threadIdx.x;
    const int w    = tid >> 6;           // wave id = column-slice id
    const int lane = tid & 63;
    const int r0   = blockIdx.x * ROWS;
    const int prow = w & (ROWS - 1);     // row this wave projects/owns

    const float st    = stepv[0];
    const float st2   = 2.0f * st;
    const float invN2 = 1.0f / ((float)NOBS * (float)NOBS);

    {
        f16x8 zv = {0, 0, 0, 0, 0, 0, 0, 0};
        for (int i = tid; i < 16 * 256 / 8; i += 256)
            *reinterpret_cast<f16x8*>(zyA + i * 8) = zv;
    }
    __syncthreads();
    {
        const _Float16 u = (_Float16)(1.0f / 256.0f);
        for (int i = tid; i < ROWS * 256; i += 256)
            zyA[i] = u;
    }

    // ---- preload B fragments: B[k][col] = Sigma[col][k] = M[col][k]-mu*mu ----
    const int colg = w * 64 + (lane & 15);
    const int ksub = (lane >> 4) * 8;
    f16x8 bfr[4][8];
#pragma unroll
    for (int n = 0; n < 4; ++n) {
        const int col = colg + n * 16;
        const float cfac = cs[col] * invN2;
#pragma unroll
        for (int kk = 0; kk < 8; ++kk) {
            const float* p  = M  + col * NY + kk * 32 + ksub;
            const float* pc = cs + kk * 32 + ksub;
            float4 lo = *reinterpret_cast<const float4*>(p);
            float4 hi = *reinterpret_cast<const float4*>(p + 4);
            float4 cl = *reinterpret_cast<const float4*>(pc);
            float4 ch = *reinterpret_cast<const float4*>(pc + 4);
            f16x8 bv;
            bv[0] = (_Float16)(lo.x - cfac * cl.x);
            bv[1] = (_Float16)(lo.y - cfac * cl.y);
            bv[2] = (_Float16)(lo.z - cfac * cl.z);
            bv[3] = (_Float16)(lo.w - cfac * cl.w);
            bv[4] = (_Float16)(hi.x - cfac * ch.x);
            bv[5] = (_Float16)(hi.y - cfac * ch.y);
            bv[6] = (_Float16)(hi.z - cfac * ch.z);
            bv[7] = (_Float16)(hi.w - cfac * ch.w);
            bfr[n][kk] = bv;
        }
    }

    f32x4 styh4, zy_own, zz;
    {
        const float* yp = yhat + (r0 + prow) * NY + lane * 4;
        f32x4 yh = *reinterpret_cast<const f32x4*>(yp);
        styh4[0] = st * yh[0]; styh4[1] = st * yh[1];
        styh4[2] = st * yh[2]; styh4[3] = st * yh[3];
    }
    const float u0 = 1.0f / 256.0f;
    zy_own[0] = u0; zy_own[1] = u0; zy_own[2] = u0; zy_own[3] = u0;
    zz = zy_own;
    float tk = 1.0f;
    float th = 0.0f;
    __syncthreads();

    for (int it = 0; it < NITER; ++it) {
        // ---- grad phase ----
        f32x4 acc[4] = {{0,0,0,0},{0,0,0,0},{0,0,0,0},{0,0,0,0}};
        const int arow  = lane & 15;
        const int abase = arow * 512;
        const int aswz  = (arow & 7) << 4;
#pragma unroll
        for (int kk = 0; kk < 8; ++kk) {
            const int aoff = (kk * 64 + (lane >> 4) * 16) ^ aswz;
            f16x8 af = *reinterpret_cast<const f16x8*>(
                reinterpret_cast<const char*>(zyA) + abase + aoff);
#pragma unroll
            for (int n = 0; n < 4; ++n)
                acc[n] = __builtin_amdgcn_mfma_f32_16x16x32_f16(af, bfr[n][kk],
                                                                acc[n], 0, 0, 0);
        }
        // ---- exchange (ablatable) ----
        if constexpr (VARIANT != 2) {
            if (lane < 16) {
#pragma unroll
                for (int r = 0; r < ROWS; ++r)
#pragma unroll
                    for (int n = 0; n < 4; ++n)
                        gbuf[r * 256 + w * 64 + n * 16 + lane] = acc[n][r];
            }
            __syncthreads();
        }

        f32x4 g4;
        if constexpr (VARIANT == 2) {
            g4[0] = acc[0][0]; g4[1] = acc[1][0];
            g4[2] = acc[2][0]; g4[3] = acc[3][0];
        } else {
            g4 = *reinterpret_cast<const f32x4*>(gbuf + prow * 256 + lane * 4);
        }
        f32x4 v4;
        v4[0] = zy_own[0] - st2 * g4[0] + styh4[0];
        v4[1] = zy_own[1] - st2 * g4[1] + styh4[1];
        v4[2] = zy_own[2] - st2 * g4[2] + styh4[2];
        v4[3] = zy_own[3] - st2 * g4[3] + styh4[3];

        // ---- Newton (ablatable) ----
        if constexpr (VARIANT == 1) {
            float d0 = v4[0] - th, d1 = v4[1] - th;
            float d2 = v4[2] - th, d3 = v4[3] - th;
            float sp = fmaxf(d0, 0.f) + fmaxf(d1, 0.f) +
                       fmaxf(d2, 0.f) + fmaxf(d3, 0.f);
            float s_tot = dpp_sum64(sp);
            int ci = __popcll(__ballot(d0 > 0.f)) + __popcll(__ballot(d1 > 0.f)) +
                     __popcll(__ballot(d2 > 0.f)) + __popcll(__ballot(d3 > 0.f));
            float cinv = __builtin_amdgcn_rcpf((float)ci);
            th = th + (s_tot - 1.0f) * cinv;     // perf probe only
        } else {
            const int newt = (it == NITER - 1) ? 24 : NEWTCAP;
            for (int nit = 0; nit < newt; ++nit) {
                float d0 = v4[0] - th, d1 = v4[1] - th;
                float d2 = v4[2] - th, d3 = v4[3] - th;
                float sp = fmaxf(d0, 0.f) + fmaxf(d1, 0.f) +
                           fmaxf(d2, 0.f) + fmaxf(d3, 0.f);
                float s_tot = dpp_sum64(sp);
                int ci = __popcll(__ballot(d0 > 0.f)) + __popcll(__ballot(d1 > 0.f)) +
                         __popcll(__ballot(d2 > 0.f)) + __popcll(__ballot(d3 > 0.f));
                if (ci == 0) {
                    float ps = dpp_sum64(v4[0] + v4[1] + v4[2] + v4[3]);
                    th = (ps - 1.0f) * (1.0f / 256.0f);
                    continue;
                }
                if (fabsf(s_tot - 1.0f) <= 1e-6f) break;
                th += (s_tot - 1.0f) / (float)ci;
            }
        }

        f32x4 zn;
        zn[0] = fmaxf(v4[0] - th, 0.f);
        zn[1] = fmaxf(v4[1] - th, 0.f);
        zn[2] = fmaxf(v4[2] - th, 0.f);
        zn[3] = fmaxf(v4[3] - th, 0.f);

        const float tn   = 0.5f * (1.0f + sqrtf(1.0f + 4.0f * tk * tk));
        const float beta = (tk - 1.0f) / tn;
        tk = tn;
        f32x4 zyn;
        zyn[0] = zn[0] + beta * (zn[0] - zz[0]);
        zyn[1] = zn[1] + beta * (zn[1] - zz[1]);
        zyn[2] = zn[2] + beta * (zn[2] - zz[2]);
        zyn[3] = zn[3] + beta * (zn[3] - zz[3]);
        zz = zn;
        zy_own = zyn;

        {
            const int off = (lane * 8) ^ ((prow & 7) << 4);
            f16x4 hz;
            hz[0] = (_Float16)zyn[0]; hz[1] = (_Float16)zyn[1];
            hz[2] = (_Float16)zyn[2]; hz[3] = (_Float16)zyn[3];
            *reinterpret_cast<f16x4*>(
                reinterpret_cast<char*>(zyA) + prow * 512 + off) = hz;
        }
        __syncthreads();
    }

    if (w < ROWS)
        *reinterpret_cast<f32x4*>(zout + (r0 + w) * NY + lane * 4) = zz;
}

// ---------------------------------------------------------------------------
extern "C" void kernel_launch(void* const* d_in, const int* in_sizes, int n_in,
                              void* d_out, int out_size, void* d_ws, size_t ws_size,
                              hipStream_t stream) {
    const float* X = (const float*)d_in[0];
    const float* Y = (const float*)d_in[1];
    const float* W = (const float*)d_in[2];
    const float* b = (const float*)d_in[3];

    float* z_out = (float*)d_out;            // (1024, 256)
    float* yhat  = z_out + NOBS * NY;        // (1024, 256) -- second output

    float* ws    = (float*)d_ws;
    float* cs    = ws;                       // 256   (column sums of ep)
    float* M     = ws + NY;                  // 65536 (uncentered 2nd moment)
    float* stepv = ws + NY + NY * NY;        // 1

    yhat_kernel<<<NOBS, 256, 0, stream>>>(X, W, b, yhat);
    sigmaM_kernel<<<NY, 256, 0, stream>>>(Y, yhat, M, cs);
    step_kernel<<<1, 1024, 0, stream>>>(M, cs, stepv);

    // ---- instrumentation dispatches (NIT=50), z region overwritten below ----
    fista_t<50, 0, 16><<<NBLK, 256, 0, stream>>>(M, cs, yhat, stepv, z_out); // V0 baseline
    fista_t<50, 1, 16><<<NBLK, 256, 0, stream>>>(M, cs, yhat, stepv, z_out); // V1 1-trip Newton
    fista_t<50, 2, 16><<<NBLK, 256, 0, stream>>>(M, cs, yhat, stepv, z_out); // V2 no exchange
    fista_t<50, 0,  3><<<NBLK, 256, 0, stream>>>(M, cs, yhat, stepv, z_out); // V4 Newton cap 3

    // ---- the real solve (overwrites all variant output deterministically) ----
    fista_t<NIT, 0, 16><<<NBLK, 256, 0, stream>>>(M, cs, yhat, stepv, z_out);
}

// Round 10
// 347.757 us; speedup vs baseline: 1.7835x; 1.7835x over previous
//
#include <hip/hip_runtime.h>
#include <math.h>

#define NOBS 1024
#define NX   128
#define NY   256
#define NIT  200
#define ROWS 2                      // rows per FISTA block
#define NBLK (NOBS / ROWS)          // 512 blocks -> 2 blocks/CU co-resident

typedef _Float16 f16x8 __attribute__((ext_vector_type(8)));
typedef _Float16 f16x4 __attribute__((ext_vector_type(4)));
typedef float    f32x4 __attribute__((ext_vector_type(4)));

// ---- fast 64-lane sum: 6 DPP adds, total lands in lane 63, readlane -> SGPR
template <int CTRL>
__device__ __forceinline__ float dpp_add(float x) {
    int yi = __builtin_amdgcn_update_dpp(0, __builtin_bit_cast(int, x),
                                         CTRL, 0xF, 0xF, true);
    return x + __builtin_bit_cast(float, yi);
}
__device__ __forceinline__ float dpp_sum64(float x) {
    x = dpp_add<0x111>(x);   // row_shr:1
    x = dpp_add<0x112>(x);   // row_shr:2
    x = dpp_add<0x114>(x);   // row_shr:4
    x = dpp_add<0x118>(x);   // row_shr:8
    x = dpp_add<0x142>(x);   // row_bcast:15
    x = dpp_add<0x143>(x);   // row_bcast:31
    return __builtin_bit_cast(float,
        __builtin_amdgcn_readlane(__builtin_bit_cast(int, x), 63));
}

// ---------------------------------------------------------------------------
// K1: Y_hat = X @ W^T + b      grid=(NOBS), block=256 (thread j -> column j)
// ---------------------------------------------------------------------------
__global__ __launch_bounds__(256) void yhat_kernel(const float* __restrict__ X,
                                                   const float* __restrict__ W,
                                                   const float* __restrict__ b,
                                                   float* __restrict__ yhat) {
    __shared__ float xs[NX];
    const int i = blockIdx.x;
    const int j = threadIdx.x;
    if (j < NX) xs[j] = X[i * NX + j];
    __syncthreads();
    const float4* wr = reinterpret_cast<const float4*>(W + j * NX);
    const float4* xr = reinterpret_cast<const float4*>(xs);
    float acc = b[j];
#pragma unroll
    for (int k = 0; k < NX / 4; ++k) {
        float4 w4 = wr[k];
        float4 x4 = xr[k];
        acc += w4.x * x4.x + w4.y * x4.y + w4.z * x4.z + w4.w * x4.w;
    }
    yhat[i * NY + j] = acc;
}

// ---------------------------------------------------------------------------
// K2: M[a][j] = (1/N) sum_i ep[i][a]*ep[i][j]; cs[a] = column sums of ep
// ---------------------------------------------------------------------------
__global__ __launch_bounds__(256) void sigmaM_kernel(const float* __restrict__ Y,
                                                     const float* __restrict__ yhat,
                                                     float* __restrict__ M,
                                                     float* __restrict__ cs) {
    const int a = blockIdx.x;
    const int j = threadIdx.x;
    __shared__ float ca[NOBS];
    for (int i = j; i < NOBS; i += 256)
        ca[i] = Y[i * NY + a] - yhat[i * NY + a];
    __syncthreads();
    float s4 = ca[j] + ca[j + 256] + ca[j + 512] + ca[j + 768];
    float wsum = dpp_sum64(s4);
    __shared__ float red[4];
    if ((j & 63) == 0) red[j >> 6] = wsum;
    __syncthreads();
    if (j == 0) cs[a] = red[0] + red[1] + red[2] + red[3];
    float s = 0.f;
#pragma unroll 4
    for (int i = 0; i < NOBS; ++i) {
        float cj = Y[i * NY + j] - yhat[i * NY + j];
        s += ca[i] * cj;
    }
    M[a * NY + j] = s * (1.0f / NOBS);
}

// ---------------------------------------------------------------------------
// K3: step = 1 / (2*||M - mu mu'||_F + 1e-8)      grid=(1), block=1024
// ---------------------------------------------------------------------------
__global__ __launch_bounds__(1024) void step_kernel(const float* __restrict__ M,
                                                    const float* __restrict__ cs,
                                                    float* __restrict__ stepv) {
    const int t = threadIdx.x;
    const float invN2 = 1.0f / ((float)NOBS * (float)NOBS);
    float s = 0.f;
    for (int idx = t; idx < NY * NY; idx += 1024) {
        const int a = idx >> 8, j = idx & 255;
        float v = M[idx] - cs[a] * cs[j] * invN2;
        s += v * v;
    }
#pragma unroll
    for (int off = 32; off; off >>= 1) s += __shfl_xor(s, off);
    __shared__ float red[16];
    if ((t & 63) == 0) red[t >> 6] = s;
    __syncthreads();
    if (t < 16) {
        float v = red[t];
#pragma unroll
        for (int off = 8; off; off >>= 1) v += __shfl_xor(v, off);
        if (t == 0) stepv[0] = 1.0f / (2.0f * sqrtf(v) + 1e-8f);
    }
}

// ---------------------------------------------------------------------------
// K4: persistent FISTA via MFMA (r7 structure) + anti-phase stagger.
// 512 blocks, 2/CU. Odd-parity blocks sleep ~half an iteration once before
// the loop so the two co-resident blocks run MFMA/VALU phases anti-phased
// (breaks the convoy; lets block A's MFMA overlap block B's projection).
// s_setprio(1) around the MFMA cluster prioritizes the MFMA-phase wave.
// ---------------------------------------------------------------------------
__global__ __launch_bounds__(256, 2) void fista_mfma_kernel(
        const float* __restrict__ M,
        const float* __restrict__ cs,
        const float* __restrict__ yhat,
        const float* __restrict__ stepv,
        float* __restrict__ zout) {
    __shared__ _Float16 zyA[16 * 256];   // A matrix, swizzled: byte ^= (row&7)<<4
    __shared__ float    gbuf[ROWS * 256]; // raw grad exchange

    const int tid  = threadIdx.x;
    const int w    = tid >> 6;           // wave id = column-slice id
    const int lane = tid & 63;
    const int r0   = blockIdx.x * ROWS;
    const int prow = w & (ROWS - 1);     // row this wave projects/owns

    const float st    = stepv[0];
    const float st2   = 2.0f * st;
    const float invN2 = 1.0f / ((float)NOBS * (float)NOBS);

    {
        f16x8 zv = {0, 0, 0, 0, 0, 0, 0, 0};
        for (int i = tid; i < 16 * 256 / 8; i += 256)
            *reinterpret_cast<f16x8*>(zyA + i * 8) = zv;
    }
    __syncthreads();
    {
        const _Float16 u = (_Float16)(1.0f / 256.0f);
        for (int i = tid; i < ROWS * 256; i += 256)
            zyA[i] = u;
    }

    // ---- preload B fragments: B[k][col] = Sigma[col][k] = M[col][k]-mu*mu ----
    const int colg = w * 64 + (lane & 15);
    const int ksub = (lane >> 4) * 8;
    f16x8 bfr[4][8];
#pragma unroll
    for (int n = 0; n < 4; ++n) {
        const int col = colg + n * 16;
        const float cfac = cs[col] * invN2;
#pragma unroll
        for (int kk = 0; kk < 8; ++kk) {
            const float* p  = M  + col * NY + kk * 32 + ksub;
            const float* pc = cs + kk * 32 + ksub;
            float4 lo = *reinterpret_cast<const float4*>(p);
            float4 hi = *reinterpret_cast<const float4*>(p + 4);
            float4 cl = *reinterpret_cast<const float4*>(pc);
            float4 ch = *reinterpret_cast<const float4*>(pc + 4);
            f16x8 bv;
            bv[0] = (_Float16)(lo.x - cfac * cl.x);
            bv[1] = (_Float16)(lo.y - cfac * cl.y);
            bv[2] = (_Float16)(lo.z - cfac * cl.z);
            bv[3] = (_Float16)(lo.w - cfac * cl.w);
            bv[4] = (_Float16)(hi.x - cfac * ch.x);
            bv[5] = (_Float16)(hi.y - cfac * ch.y);
            bv[6] = (_Float16)(hi.z - cfac * ch.z);
            bv[7] = (_Float16)(hi.w - cfac * ch.w);
            bfr[n][kk] = bv;
        }
    }

    f32x4 styh4, zy_own, zz;
    {
        const float* yp = yhat + (r0 + prow) * NY + lane * 4;
        f32x4 yh = *reinterpret_cast<const f32x4*>(yp);
        styh4[0] = st * yh[0]; styh4[1] = st * yh[1];
        styh4[2] = st * yh[2]; styh4[3] = st * yh[3];
    }
    const float u0 = 1.0f / 256.0f;
    zy_own[0] = u0; zy_own[1] = u0; zy_own[2] = u0; zy_own[3] = u0;
    zz = zy_own;
    float tk = 1.0f;
    float th = 0.0f;
    __syncthreads();

    // ---- anti-phase stagger: half-period one-time delay for half the blocks.
    // parity key flips under either plausible same-CU pairing: (2i,2i+1) via
    // bit0, (i,i+256) via bit8.
    if (((blockIdx.x ^ (blockIdx.x >> 8)) & 1) != 0) {
        __builtin_amdgcn_s_sleep(26);   // ~26*64 = 1664 cycles ~ half iter
    }

    for (int it = 0; it < NIT; ++it) {
        // ---- grad phase: acc[n] = (Zy @ Sigma) tile (16x16), K=256 ----
        f32x4 acc[4] = {{0,0,0,0},{0,0,0,0},{0,0,0,0},{0,0,0,0}};
        const int arow  = lane & 15;
        const int abase = arow * 512;
        const int aswz  = (arow & 7) << 4;
        __builtin_amdgcn_s_setprio(1);
#pragma unroll
        for (int kk = 0; kk < 8; ++kk) {
            const int aoff = (kk * 64 + (lane >> 4) * 16) ^ aswz;
            f16x8 af = *reinterpret_cast<const f16x8*>(
                reinterpret_cast<const char*>(zyA) + abase + aoff);
#pragma unroll
            for (int n = 0; n < 4; ++n)
                acc[n] = __builtin_amdgcn_mfma_f32_16x16x32_f16(af, bfr[n][kk],
                                                                acc[n], 0, 0, 0);
        }
        __builtin_amdgcn_s_setprio(0);
        // ---- epilogue: pure dump of raw grad ----
        if (lane < 16) {
#pragma unroll
            for (int r = 0; r < ROWS; ++r)
#pragma unroll
                for (int n = 0; n < 4; ++n)
                    gbuf[r * 256 + w * 64 + n * 16 + lane] = acc[n][r];
        }
        __syncthreads();

        // ---- projection: v from regs + one LDS read of g ----
        f32x4 g4 = *reinterpret_cast<const f32x4*>(gbuf + prow * 256 + lane * 4);
        f32x4 v4;
        v4[0] = zy_own[0] - st2 * g4[0] + styh4[0];
        v4[1] = zy_own[1] - st2 * g4[1] + styh4[1];
        v4[2] = zy_own[2] - st2 * g4[2] + styh4[2];
        v4[3] = zy_own[3] - st2 * g4[3] + styh4[3];

        // warm-started Newton with early exit; th0 restart computed lazily
        const int newt = (it == NIT - 1) ? 24 : 16;
        for (int nit = 0; nit < newt; ++nit) {
            float d0 = v4[0] - th, d1 = v4[1] - th;
            float d2 = v4[2] - th, d3 = v4[3] - th;
            float sp = fmaxf(d0, 0.f) + fmaxf(d1, 0.f) +
                       fmaxf(d2, 0.f) + fmaxf(d3, 0.f);
            float s_tot = dpp_sum64(sp);                    // uniform (SGPR)
            int ci = __popcll(__ballot(d0 > 0.f)) + __popcll(__ballot(d1 > 0.f)) +
                     __popcll(__ballot(d2 > 0.f)) + __popcll(__ballot(d3 > 0.f));
            if (ci == 0) {                                  // rare: overshot
                float ps = dpp_sum64(v4[0] + v4[1] + v4[2] + v4[3]);
                th = (ps - 1.0f) * (1.0f / 256.0f);
                continue;
            }
            if (fabsf(s_tot - 1.0f) <= 1e-6f) break;        // converged
            th += (s_tot - 1.0f) / (float)ci;               // Newton step
        }

        f32x4 zn;
        zn[0] = fmaxf(v4[0] - th, 0.f);
        zn[1] = fmaxf(v4[1] - th, 0.f);
        zn[2] = fmaxf(v4[2] - th, 0.f);
        zn[3] = fmaxf(v4[3] - th, 0.f);

        const float tn   = 0.5f * (1.0f + sqrtf(1.0f + 4.0f * tk * tk));
        const float beta = (tk - 1.0f) / tn;
        tk = tn;
        f32x4 zyn;
        zyn[0] = zn[0] + beta * (zn[0] - zz[0]);
        zyn[1] = zn[1] + beta * (zn[1] - zz[1]);
        zyn[2] = zn[2] + beta * (zn[2] - zz[2]);
        zyn[3] = zn[3] + beta * (zn[3] - zz[3]);
        zz = zn;
        zy_own = zyn;

        // write zyn f16 -> zyA (swizzled row prow); duplicate waves write
        // identical bits (benign race)
        {
            const int off = (lane * 8) ^ ((prow & 7) << 4);
            f16x4 hz;
            hz[0] = (_Float16)zyn[0]; hz[1] = (_Float16)zyn[1];
            hz[2] = (_Float16)zyn[2]; hz[3] = (_Float16)zyn[3];
            *reinterpret_cast<f16x4*>(
                reinterpret_cast<char*>(zyA) + prow * 512 + off) = hz;
        }
        __syncthreads();
    }

    // ---- output: waves 0..ROWS-1 write their rows ----
    if (w < ROWS)
        *reinterpret_cast<f32x4*>(zout + (r0 + w) * NY + lane * 4) = zz;
}

// ---------------------------------------------------------------------------
extern "C" void kernel_launch(void* const* d_in, const int* in_sizes, int n_in,
                              void* d_out, int out_size, void* d_ws, size_t ws_size,
                              hipStream_t stream) {
    const float* X = (const float*)d_in[0];
    const float* Y = (const float*)d_in[1];
    const float* W = (const float*)d_in[2];
    const float* b = (const float*)d_in[3];

    float* z_out = (float*)d_out;            // (1024, 256)
    float* yhat  = z_out + NOBS * NY;        // (1024, 256) -- second output

    float* ws    = (float*)d_ws;
    float* cs    = ws;                       // 256   (column sums of ep)
    float* M     = ws + NY;                  // 65536 (uncentered 2nd moment)
    float* stepv = ws + NY + NY * NY;        // 1

    yhat_kernel<<<NOBS, 256, 0, stream>>>(X, W, b, yhat);
    sigmaM_kernel<<<NY, 256, 0, stream>>>(Y, yhat, M, cs);
    step_kernel<<<1, 1024, 0, stream>>>(M, cs, stepv);
    fista_mfma_kernel<<<NBLK, 256, 0, stream>>>(M, cs, yhat, stepv, z_out);
}

// Round 11
// 318.028 us; speedup vs baseline: 1.9502x; 1.0935x over previous
//
#include <hip/hip_runtime.h>
#include <math.h>

#define NOBS 1024
#define NX   128
#define NY   256
#define NIT  200
#define ROWS 4                      // rows per FISTA block
#define NBLK (NOBS / ROWS)          // 256 blocks -> 1 block/CU

typedef _Float16 f16x8 __attribute__((ext_vector_type(8)));
typedef _Float16 f16x4 __attribute__((ext_vector_type(4)));
typedef float    f32x4 __attribute__((ext_vector_type(4)));

// ---- fast 64-lane sum: 6 DPP adds, total lands in lane 63, readlane -> SGPR
template <int CTRL>
__device__ __forceinline__ float dpp_add(float x) {
    int yi = __builtin_amdgcn_update_dpp(0, __builtin_bit_cast(int, x),
                                         CTRL, 0xF, 0xF, true);
    return x + __builtin_bit_cast(float, yi);
}
__device__ __forceinline__ float dpp_sum64(float x) {
    x = dpp_add<0x111>(x);   // row_shr:1
    x = dpp_add<0x112>(x);   // row_shr:2
    x = dpp_add<0x114>(x);   // row_shr:4
    x = dpp_add<0x118>(x);   // row_shr:8
    x = dpp_add<0x142>(x);   // row_bcast:15
    x = dpp_add<0x143>(x);   // row_bcast:31
    return __builtin_bit_cast(float,
        __builtin_amdgcn_readlane(__builtin_bit_cast(int, x), 63));
}

// ---------------------------------------------------------------------------
// K1: Y_hat = X @ W^T + b      grid=(NOBS), block=256 (thread j -> column j)
// ---------------------------------------------------------------------------
__global__ __launch_bounds__(256) void yhat_kernel(const float* __restrict__ X,
                                                   const float* __restrict__ W,
                                                   const float* __restrict__ b,
                                                   float* __restrict__ yhat) {
    __shared__ float xs[NX];
    const int i = blockIdx.x;
    const int j = threadIdx.x;
    if (j < NX) xs[j] = X[i * NX + j];
    __syncthreads();
    const float4* wr = reinterpret_cast<const float4*>(W + j * NX);
    const float4* xr = reinterpret_cast<const float4*>(xs);
    float acc = b[j];
#pragma unroll
    for (int k = 0; k < NX / 4; ++k) {
        float4 w4 = wr[k];
        float4 x4 = xr[k];
        acc += w4.x * x4.x + w4.y * x4.y + w4.z * x4.z + w4.w * x4.w;
    }
    yhat[i * NY + j] = acc;
}

// ---------------------------------------------------------------------------
// K2: M[a][j] = (1/N) sum_i ep[i][a]*ep[i][j]; cs[a] = column sums of ep
// ---------------------------------------------------------------------------
__global__ __launch_bounds__(256) void sigmaM_kernel(const float* __restrict__ Y,
                                                     const float* __restrict__ yhat,
                                                     float* __restrict__ M,
                                                     float* __restrict__ cs) {
    const int a = blockIdx.x;
    const int j = threadIdx.x;
    __shared__ float ca[NOBS];
    for (int i = j; i < NOBS; i += 256)
        ca[i] = Y[i * NY + a] - yhat[i * NY + a];
    __syncthreads();
    float s4 = ca[j] + ca[j + 256] + ca[j + 512] + ca[j + 768];
    float wsum = dpp_sum64(s4);
    __shared__ float red[4];
    if ((j & 63) == 0) red[j >> 6] = wsum;
    __syncthreads();
    if (j == 0) cs[a] = red[0] + red[1] + red[2] + red[3];
    float s = 0.f;
#pragma unroll 4
    for (int i = 0; i < NOBS; ++i) {
        float cj = Y[i * NY + j] - yhat[i * NY + j];
        s += ca[i] * cj;
    }
    M[a * NY + j] = s * (1.0f / NOBS);
}

// ---------------------------------------------------------------------------
// K3: step = 1 / (2*||M - mu mu'||_F + 1e-8)      grid=(1), block=1024
// ---------------------------------------------------------------------------
__global__ __launch_bounds__(1024) void step_kernel(const float* __restrict__ M,
                                                    const float* __restrict__ cs,
                                                    float* __restrict__ stepv) {
    const int t = threadIdx.x;
    const float invN2 = 1.0f / ((float)NOBS * (float)NOBS);
    float s = 0.f;
    for (int idx = t; idx < NY * NY; idx += 1024) {
        const int a = idx >> 8, j = idx & 255;
        float v = M[idx] - cs[a] * cs[j] * invN2;
        s += v * v;
    }
#pragma unroll
    for (int off = 32; off; off >>= 1) s += __shfl_xor(s, off);
    __shared__ float red[16];
    if ((t & 63) == 0) red[t >> 6] = s;
    __syncthreads();
    if (t < 16) {
        float v = red[t];
#pragma unroll
        for (int off = 8; off; off >>= 1) v += __shfl_xor(v, off);
        if (t == 0) stepv[0] = 1.0f / (2.0f * sqrtf(v) + 1e-8f);
    }
}

// ---------------------------------------------------------------------------
// K4: persistent FISTA via MFMA. grid=256 blocks (1/CU), 256 threads (4 waves).
// Block owns 4 rows; wave w owns B-columns [64w,64w+64) in f16 regs and
// projects row w. KEY CHANGE vs r7: all 8 A-fragments are prefetched into
// registers BEFORE the MFMA burst (8 back-to-back ds_read_b128), breaking the
// per-kk ds_read->lgkmcnt(0)->MFMA serialization (~120cyc x 8 on the chain).
// ---------------------------------------------------------------------------
__global__ __launch_bounds__(256, 1) void fista_mfma_kernel(
        const float* __restrict__ M,
        const float* __restrict__ cs,
        const float* __restrict__ yhat,
        const float* __restrict__ stepv,
        float* __restrict__ zout) {
    __shared__ _Float16 zyA[16 * 256];    // A matrix, swizzled: byte ^= (row&7)<<4
    __shared__ float    gbuf[ROWS * 264]; // grad exchange, padded rows

    const int tid  = threadIdx.x;
    const int w    = tid >> 6;           // wave id = column-slice id = row id
    const int lane = tid & 63;
    const int r0   = blockIdx.x * ROWS;

    const float st    = stepv[0];
    const float st2   = 2.0f * st;
    const float invN2 = 1.0f / ((float)NOBS * (float)NOBS);

    {
        f16x8 zv = {0, 0, 0, 0, 0, 0, 0, 0};
        for (int i = tid; i < 16 * 256 / 8; i += 256)
            *reinterpret_cast<f16x8*>(zyA + i * 8) = zv;
    }
    __syncthreads();
    {
        const _Float16 u = (_Float16)(1.0f / 256.0f);
        for (int i = tid; i < ROWS * 256; i += 256)   // rows 0..3 uniform fill
            zyA[i] = u;                               // (swizzle-invariant)
    }

    // ---- preload B fragments: B[k][col] = Sigma[col][k] = M[col][k]-mu*mu ----
    const int colg = w * 64 + (lane & 15);
    const int ksub = (lane >> 4) * 8;
    f16x8 bfr[4][8];
#pragma unroll
    for (int n = 0; n < 4; ++n) {
        const int col = colg + n * 16;
        const float cfac = cs[col] * invN2;
#pragma unroll
        for (int kk = 0; kk < 8; ++kk) {
            const float* p  = M  + col * NY + kk * 32 + ksub;
            const float* pc = cs + kk * 32 + ksub;
            float4 lo = *reinterpret_cast<const float4*>(p);
            float4 hi = *reinterpret_cast<const float4*>(p + 4);
            float4 cl = *reinterpret_cast<const float4*>(pc);
            float4 ch = *reinterpret_cast<const float4*>(pc + 4);
            f16x8 bv;
            bv[0] = (_Float16)(lo.x - cfac * cl.x);
            bv[1] = (_Float16)(lo.y - cfac * cl.y);
            bv[2] = (_Float16)(lo.z - cfac * cl.z);
            bv[3] = (_Float16)(lo.w - cfac * cl.w);
            bv[4] = (_Float16)(hi.x - cfac * ch.x);
            bv[5] = (_Float16)(hi.y - cfac * ch.y);
            bv[6] = (_Float16)(hi.z - cfac * ch.z);
            bv[7] = (_Float16)(hi.w - cfac * ch.w);
            bfr[n][kk] = bv;
        }
    }

    // ---- per-wave owned row state (regs) ----
    f32x4 styh4, zy_own, zz;
    {
        const float* yp = yhat + (r0 + w) * NY + lane * 4;
        f32x4 yh = *reinterpret_cast<const f32x4*>(yp);
        styh4[0] = st * yh[0]; styh4[1] = st * yh[1];
        styh4[2] = st * yh[2]; styh4[3] = st * yh[3];
    }
    const float u0 = 1.0f / 256.0f;
    zy_own[0] = u0; zy_own[1] = u0; zy_own[2] = u0; zy_own[3] = u0;
    zz = zy_own;
    float tk = 1.0f;
    float th = 0.0f;                      // warm-started simplex threshold
    __syncthreads();

    const int arow  = lane & 15;
    const int abase = arow * 512;
    const int aswz  = (arow & 7) << 4;

    for (int it = 0; it < NIT; ++it) {
        // ---- PREFETCH all 8 A-fragments (back-to-back ds_read_b128) ----
        f16x8 af[8];
#pragma unroll
        for (int kk = 0; kk < 8; ++kk) {
            const int aoff = (kk * 64 + (lane >> 4) * 16) ^ aswz;
            af[kk] = *reinterpret_cast<const f16x8*>(
                reinterpret_cast<const char*>(zyA) + abase + aoff);
        }
        // ---- MFMA burst: 32 MFMAs, 4 independent acc chains ----
        f32x4 acc[4] = {{0,0,0,0},{0,0,0,0},{0,0,0,0},{0,0,0,0}};
#pragma unroll
        for (int kk = 0; kk < 8; ++kk) {
#pragma unroll
            for (int n = 0; n < 4; ++n)
                acc[n] = __builtin_amdgcn_mfma_f32_16x16x32_f16(af[kk], bfr[n][kk],
                                                                acc[n], 0, 0, 0);
        }
        // ---- epilogue: pure dump of raw grad rows 0..3 ----
        if (lane < 16) {
#pragma unroll
            for (int r = 0; r < ROWS; ++r)
#pragma unroll
                for (int n = 0; n < 4; ++n)
                    gbuf[r * 264 + w * 64 + n * 16 + lane] = acc[n][r];
        }
        __syncthreads();

        // ---- projection: v from regs + one LDS read of g (row w) ----
        f32x4 g4 = *reinterpret_cast<const f32x4*>(gbuf + w * 264 + lane * 4);
        f32x4 v4;
        v4[0] = zy_own[0] - st2 * g4[0] + styh4[0];
        v4[1] = zy_own[1] - st2 * g4[1] + styh4[1];
        v4[2] = zy_own[2] - st2 * g4[2] + styh4[2];
        v4[3] = zy_own[3] - st2 * g4[3] + styh4[3];

        // warm-started Newton with early exit; th0 restart computed lazily
        const int newt = (it == NIT - 1) ? 24 : 16;
        for (int nit = 0; nit < newt; ++nit) {
            float d0 = v4[0] - th, d1 = v4[1] - th;
            float d2 = v4[2] - th, d3 = v4[3] - th;
            float sp = fmaxf(d0, 0.f) + fmaxf(d1, 0.f) +
                       fmaxf(d2, 0.f) + fmaxf(d3, 0.f);
            float s_tot = dpp_sum64(sp);                    // uniform (SGPR)
            int ci = __popcll(__ballot(d0 > 0.f)) + __popcll(__ballot(d1 > 0.f)) +
                     __popcll(__ballot(d2 > 0.f)) + __popcll(__ballot(d3 > 0.f));
            if (ci == 0) {                                  // rare: overshot
                float ps = dpp_sum64(v4[0] + v4[1] + v4[2] + v4[3]);
                th = (ps - 1.0f) * (1.0f / 256.0f);
                continue;
            }
            if (fabsf(s_tot - 1.0f) <= 1e-6f) break;        // converged
            th += (s_tot - 1.0f) / (float)ci;               // Newton step
        }

        f32x4 zn;
        zn[0] = fmaxf(v4[0] - th, 0.f);
        zn[1] = fmaxf(v4[1] - th, 0.f);
        zn[2] = fmaxf(v4[2] - th, 0.f);
        zn[3] = fmaxf(v4[3] - th, 0.f);

        const float tn   = 0.5f * (1.0f + sqrtf(1.0f + 4.0f * tk * tk));
        const float beta = (tk - 1.0f) / tn;
        tk = tn;
        f32x4 zyn;
        zyn[0] = zn[0] + beta * (zn[0] - zz[0]);
        zyn[1] = zn[1] + beta * (zn[1] - zz[1]);
        zyn[2] = zn[2] + beta * (zn[2] - zz[2]);
        zyn[3] = zn[3] + beta * (zn[3] - zz[3]);
        zz = zn;
        zy_own = zyn;

        // write zyn f16 -> zyA (swizzled row w)
        {
            const int off = (lane * 8) ^ ((w & 7) << 4);
            f16x4 hz;
            hz[0] = (_Float16)zyn[0]; hz[1] = (_Float16)zyn[1];
            hz[2] = (_Float16)zyn[2]; hz[3] = (_Float16)zyn[3];
            *reinterpret_cast<f16x4*>(
                reinterpret_cast<char*>(zyA) + w * 512 + off) = hz;
        }
        __syncthreads();
    }

    // ---- output: wave w writes row r0+w ----
    *reinterpret_cast<f32x4*>(zout + (r0 + w) * NY + lane * 4) = zz;
}

// ---------------------------------------------------------------------------
extern "C" void kernel_launch(void* const* d_in, const int* in_sizes, int n_in,
                              void* d_out, int out_size, void* d_ws, size_t ws_size,
                              hipStream_t stream) {
    const float* X = (const float*)d_in[0];
    const float* Y = (const float*)d_in[1];
    const float* W = (const float*)d_in[2];
    const float* b = (const float*)d_in[3];

    float* z_out = (float*)d_out;            // (1024, 256)
    float* yhat  = z_out + NOBS * NY;        // (1024, 256) -- second output

    float* ws    = (float*)d_ws;
    float* cs    = ws;                       // 256   (column sums of ep)
    float* M     = ws + NY;                  // 65536 (uncentered 2nd moment)
    float* stepv = ws + NY + NY * NY;        // 1

    yhat_kernel<<<NOBS, 256, 0, stream>>>(X, W, b, yhat);
    sigmaM_kernel<<<NY, 256, 0, stream>>>(Y, yhat, M, cs);
    step_kernel<<<1, 1024, 0, stream>>>(M, cs, stepv);
    fista_mfma_kernel<<<NBLK, 256, 0, stream>>>(M, cs, yhat, stepv, z_out);
}

// Round 12
// 312.109 us; speedup vs baseline: 1.9872x; 1.0190x over previous
//
#include <hip/hip_runtime.h>
#include <math.h>

#define NOBS 1024
#define NX   128
#define NY   256
#define NIT  200
#define ROWS 4                      // rows per FISTA block
#define NBLK (NOBS / ROWS)          // 256 blocks -> 1 block/CU

typedef _Float16 f16x8 __attribute__((ext_vector_type(8)));
typedef _Float16 f16x4 __attribute__((ext_vector_type(4)));
typedef float    f32x4 __attribute__((ext_vector_type(4)));

// ---- fast 64-lane sum: 6 DPP adds, total lands in lane 63, readlane -> SGPR
template <int CTRL>
__device__ __forceinline__ float dpp_add(float x) {
    int yi = __builtin_amdgcn_update_dpp(0, __builtin_bit_cast(int, x),
                                         CTRL, 0xF, 0xF, true);
    return x + __builtin_bit_cast(float, yi);
}
__device__ __forceinline__ float dpp_sum64(float x) {
    x = dpp_add<0x111>(x);   // row_shr:1
    x = dpp_add<0x112>(x);   // row_shr:2
    x = dpp_add<0x114>(x);   // row_shr:4
    x = dpp_add<0x118>(x);   // row_shr:8
    x = dpp_add<0x142>(x);   // row_bcast:15
    x = dpp_add<0x143>(x);   // row_bcast:31
    return __builtin_bit_cast(float,
        __builtin_amdgcn_readlane(__builtin_bit_cast(int, x), 63));
}

// ---------------------------------------------------------------------------
// K1: Y_hat = X @ W^T + b      grid=(NOBS), block=256 (thread j -> column j)
// ---------------------------------------------------------------------------
__global__ __launch_bounds__(256) void yhat_kernel(const float* __restrict__ X,
                                                   const float* __restrict__ W,
                                                   const float* __restrict__ b,
                                                   float* __restrict__ yhat) {
    __shared__ float xs[NX];
    const int i = blockIdx.x;
    const int j = threadIdx.x;
    if (j < NX) xs[j] = X[i * NX + j];
    __syncthreads();
    const float4* wr = reinterpret_cast<const float4*>(W + j * NX);
    const float4* xr = reinterpret_cast<const float4*>(xs);
    float acc = b[j];
#pragma unroll
    for (int k = 0; k < NX / 4; ++k) {
        float4 w4 = wr[k];
        float4 x4 = xr[k];
        acc += w4.x * x4.x + w4.y * x4.y + w4.z * x4.z + w4.w * x4.w;
    }
    yhat[i * NY + j] = acc;
}

// ---------------------------------------------------------------------------
// K2: M[a][j] = (1/N) sum_i ep[i][a]*ep[i][j]; cs[a] = column sums of ep
// ---------------------------------------------------------------------------
__global__ __launch_bounds__(256) void sigmaM_kernel(const float* __restrict__ Y,
                                                     const float* __restrict__ yhat,
                                                     float* __restrict__ M,
                                                     float* __restrict__ cs) {
    const int a = blockIdx.x;
    const int j = threadIdx.x;
    __shared__ float ca[NOBS];
    for (int i = j; i < NOBS; i += 256)
        ca[i] = Y[i * NY + a] - yhat[i * NY + a];
    __syncthreads();
    float s4 = ca[j] + ca[j + 256] + ca[j + 512] + ca[j + 768];
    float wsum = dpp_sum64(s4);
    __shared__ float red[4];
    if ((j & 63) == 0) red[j >> 6] = wsum;
    __syncthreads();
    if (j == 0) cs[a] = red[0] + red[1] + red[2] + red[3];
    float s = 0.f;
#pragma unroll 4
    for (int i = 0; i < NOBS; ++i) {
        float cj = Y[i * NY + j] - yhat[i * NY + j];
        s += ca[i] * cj;
    }
    M[a * NY + j] = s * (1.0f / NOBS);
}

// ---------------------------------------------------------------------------
// K3: step = 1 / (2*||M - mu mu'||_F + 1e-8)      grid=(1), block=1024
// ---------------------------------------------------------------------------
__global__ __launch_bounds__(1024) void step_kernel(const float* __restrict__ M,
                                                    const float* __restrict__ cs,
                                                    float* __restrict__ stepv) {
    const int t = threadIdx.x;
    const float invN2 = 1.0f / ((float)NOBS * (float)NOBS);
    float s = 0.f;
    for (int idx = t; idx < NY * NY; idx += 1024) {
        const int a = idx >> 8, j = idx & 255;
        float v = M[idx] - cs[a] * cs[j] * invN2;
        s += v * v;
    }
#pragma unroll
    for (int off = 32; off; off >>= 1) s += __shfl_xor(s, off);
    __shared__ float red[16];
    if ((t & 63) == 0) red[t >> 6] = s;
    __syncthreads();
    if (t < 16) {
        float v = red[t];
#pragma unroll
        for (int off = 8; off; off >>= 1) v += __shfl_xor(v, off);
        if (t == 0) stepv[0] = 1.0f / (2.0f * sqrtf(v) + 1e-8f);
    }
}

// ---------------------------------------------------------------------------
// K4: persistent FISTA via MFMA. grid=256 blocks (1/CU), 256 threads (4 waves).
// Block owns 4 rows; wave w owns B-columns [64w,64w+64) in f16 regs and
// projects row w. r12 changes vs r11:
//  (a) acc chains split even/odd kk: 8 chains x 4-deep (MFMA latency-bound fix)
//  (b) mid-stream Newton = FIXED 3 branchless trips (identical instruction
//      stream on all waves -> no slowest-wave barrier penalty; v_rcp divide).
//      Final iteration keeps the exact 24-trip early-exit solve.
// ---------------------------------------------------------------------------
__global__ __launch_bounds__(256, 1) void fista_mfma_kernel(
        const float* __restrict__ M,
        const float* __restrict__ cs,
        const float* __restrict__ yhat,
        const float* __restrict__ stepv,
        float* __restrict__ zout) {
    __shared__ _Float16 zyA[16 * 256];    // A matrix, swizzled: byte ^= (row&7)<<4
    __shared__ float    gbuf[ROWS * 264]; // grad exchange, padded rows

    const int tid  = threadIdx.x;
    const int w    = tid >> 6;           // wave id = column-slice id = row id
    const int lane = tid & 63;
    const int r0   = blockIdx.x * ROWS;

    const float st    = stepv[0];
    const float st2   = 2.0f * st;
    const float invN2 = 1.0f / ((float)NOBS * (float)NOBS);

    {
        f16x8 zv = {0, 0, 0, 0, 0, 0, 0, 0};
        for (int i = tid; i < 16 * 256 / 8; i += 256)
            *reinterpret_cast<f16x8*>(zyA + i * 8) = zv;
    }
    __syncthreads();
    {
        const _Float16 u = (_Float16)(1.0f / 256.0f);
        for (int i = tid; i < ROWS * 256; i += 256)   // rows 0..3 uniform fill
            zyA[i] = u;                               // (swizzle-invariant)
    }

    // ---- preload B fragments: B[k][col] = Sigma[col][k] = M[col][k]-mu*mu ----
    const int colg = w * 64 + (lane & 15);
    const int ksub = (lane >> 4) * 8;
    f16x8 bfr[4][8];
#pragma unroll
    for (int n = 0; n < 4; ++n) {
        const int col = colg + n * 16;
        const float cfac = cs[col] * invN2;
#pragma unroll
        for (int kk = 0; kk < 8; ++kk) {
            const float* p  = M  + col * NY + kk * 32 + ksub;
            const float* pc = cs + kk * 32 + ksub;
            float4 lo = *reinterpret_cast<const float4*>(p);
            float4 hi = *reinterpret_cast<const float4*>(p + 4);
            float4 cl = *reinterpret_cast<const float4*>(pc);
            float4 ch = *reinterpret_cast<const float4*>(pc + 4);
            f16x8 bv;
            bv[0] = (_Float16)(lo.x - cfac * cl.x);
            bv[1] = (_Float16)(lo.y - cfac * cl.y);
            bv[2] = (_Float16)(lo.z - cfac * cl.z);
            bv[3] = (_Float16)(lo.w - cfac * cl.w);
            bv[4] = (_Float16)(hi.x - cfac * ch.x);
            bv[5] = (_Float16)(hi.y - cfac * ch.y);
            bv[6] = (_Float16)(hi.z - cfac * ch.z);
            bv[7] = (_Float16)(hi.w - cfac * ch.w);
            bfr[n][kk] = bv;
        }
    }

    // ---- per-wave owned row state (regs) ----
    f32x4 styh4, zy_own, zz;
    {
        const float* yp = yhat + (r0 + w) * NY + lane * 4;
        f32x4 yh = *reinterpret_cast<const f32x4*>(yp);
        styh4[0] = st * yh[0]; styh4[1] = st * yh[1];
        styh4[2] = st * yh[2]; styh4[3] = st * yh[3];
    }
    const float u0 = 1.0f / 256.0f;
    zy_own[0] = u0; zy_own[1] = u0; zy_own[2] = u0; zy_own[3] = u0;
    zz = zy_own;
    float tk = 1.0f;
    float th = 0.0f;                      // warm-started simplex threshold
    __syncthreads();

    const int arow  = lane & 15;
    const int abase = arow * 512;
    const int aswz  = (arow & 7) << 4;

    for (int it = 0; it < NIT; ++it) {
        // ---- PREFETCH all 8 A-fragments (back-to-back ds_read_b128) ----
        f16x8 af[8];
#pragma unroll
        for (int kk = 0; kk < 8; ++kk) {
            const int aoff = (kk * 64 + (lane >> 4) * 16) ^ aswz;
            af[kk] = *reinterpret_cast<const f16x8*>(
                reinterpret_cast<const char*>(zyA) + abase + aoff);
        }
        // ---- MFMA burst: 8 independent chains, 4-deep each ----
        f32x4 accA[4] = {{0,0,0,0},{0,0,0,0},{0,0,0,0},{0,0,0,0}};
        f32x4 accB[4] = {{0,0,0,0},{0,0,0,0},{0,0,0,0},{0,0,0,0}};
#pragma unroll
        for (int kk = 0; kk < 8; kk += 2) {
#pragma unroll
            for (int n = 0; n < 4; ++n) {
                accA[n] = __builtin_amdgcn_mfma_f32_16x16x32_f16(af[kk],     bfr[n][kk],
                                                                 accA[n], 0, 0, 0);
                accB[n] = __builtin_amdgcn_mfma_f32_16x16x32_f16(af[kk + 1], bfr[n][kk + 1],
                                                                 accB[n], 0, 0, 0);
            }
        }
        // ---- epilogue: pure dump of raw grad rows 0..3 ----
        if (lane < 16) {
#pragma unroll
            for (int r = 0; r < ROWS; ++r)
#pragma unroll
                for (int n = 0; n < 4; ++n)
                    gbuf[r * 264 + w * 64 + n * 16 + lane] = accA[n][r] + accB[n][r];
        }
        __syncthreads();

        // ---- projection: v from regs + one LDS read of g (row w) ----
        f32x4 g4 = *reinterpret_cast<const f32x4*>(gbuf + w * 264 + lane * 4);
        f32x4 v4;
        v4[0] = zy_own[0] - st2 * g4[0] + styh4[0];
        v4[1] = zy_own[1] - st2 * g4[1] + styh4[1];
        v4[2] = zy_own[2] - st2 * g4[2] + styh4[2];
        v4[3] = zy_own[3] - st2 * g4[3] + styh4[3];

        if (it != NIT - 1) {
            // ---- FIXED 3-trip branchless Newton (uniform across waves) ----
            float ps   = dpp_sum64(v4[0] + v4[1] + v4[2] + v4[3]);
            float th0n = (ps - 1.0f) * (1.0f / 256.0f);   // lower bound on th*
#pragma unroll
            for (int nit = 0; nit < 3; ++nit) {
                float d0 = v4[0] - th, d1 = v4[1] - th;
                float d2 = v4[2] - th, d3 = v4[3] - th;
                float sp = fmaxf(d0, 0.f) + fmaxf(d1, 0.f) +
                           fmaxf(d2, 0.f) + fmaxf(d3, 0.f);
                float s_tot = dpp_sum64(sp);
                int ci = __popcll(__ballot(d0 > 0.f)) + __popcll(__ballot(d1 > 0.f)) +
                         __popcll(__ballot(d2 > 0.f)) + __popcll(__ballot(d3 > 0.f));
                float cf   = fmaxf((float)ci, 1.0f);
                float thn  = th + (s_tot - 1.0f) * __builtin_amdgcn_rcpf(cf);
                th = (ci == 0) ? th0n : thn;               // branchless restart
            }
        } else {
            // ---- final iteration: exact solve, early exit ----
            for (int nit = 0; nit < 24; ++nit) {
                float d0 = v4[0] - th, d1 = v4[1] - th;
                float d2 = v4[2] - th, d3 = v4[3] - th;
                float sp = fmaxf(d0, 0.f) + fmaxf(d1, 0.f) +
                           fmaxf(d2, 0.f) + fmaxf(d3, 0.f);
                float s_tot = dpp_sum64(sp);
                int ci = __popcll(__ballot(d0 > 0.f)) + __popcll(__ballot(d1 > 0.f)) +
                         __popcll(__ballot(d2 > 0.f)) + __popcll(__ballot(d3 > 0.f));
                if (ci == 0) {
                    float ps = dpp_sum64(v4[0] + v4[1] + v4[2] + v4[3]);
                    th = (ps - 1.0f) * (1.0f / 256.0f);
                    continue;
                }
                if (fabsf(s_tot - 1.0f) <= 1e-6f) break;
                th += (s_tot - 1.0f) / (float)ci;
            }
        }

        f32x4 zn;
        zn[0] = fmaxf(v4[0] - th, 0.f);
        zn[1] = fmaxf(v4[1] - th, 0.f);
        zn[2] = fmaxf(v4[2] - th, 0.f);
        zn[3] = fmaxf(v4[3] - th, 0.f);

        const float tn   = 0.5f * (1.0f + sqrtf(1.0f + 4.0f * tk * tk));
        const float beta = (tk - 1.0f) / tn;
        tk = tn;
        f32x4 zyn;
        zyn[0] = zn[0] + beta * (zn[0] - zz[0]);
        zyn[1] = zn[1] + beta * (zn[1] - zz[1]);
        zyn[2] = zn[2] + beta * (zn[2] - zz[2]);
        zyn[3] = zn[3] + beta * (zn[3] - zz[3]);
        zz = zn;
        zy_own = zyn;

        // write zyn f16 -> zyA (swizzled row w)
        {
            const int off = (lane * 8) ^ ((w & 7) << 4);
            f16x4 hz;
            hz[0] = (_Float16)zyn[0]; hz[1] = (_Float16)zyn[1];
            hz[2] = (_Float16)zyn[2]; hz[3] = (_Float16)zyn[3];
            *reinterpret_cast<f16x4*>(
                reinterpret_cast<char*>(zyA) + w * 512 + off) = hz;
        }
        __syncthreads();
    }

    // ---- output: wave w writes row r0+w ----
    *reinterpret_cast<f32x4*>(zout + (r0 + w) * NY + lane * 4) = zz;
}

// ---------------------------------------------------------------------------
extern "C" void kernel_launch(void* const* d_in, const int* in_sizes, int n_in,
                              void* d_out, int out_size, void* d_ws, size_t ws_size,
                              hipStream_t stream) {
    const float* X = (const float*)d_in[0];
    const float* Y = (const float*)d_in[1];
    const float* W = (const float*)d_in[2];
    const float* b = (const float*)d_in[3];

    float* z_out = (float*)d_out;            // (1024, 256)
    float* yhat  = z_out + NOBS * NY;        // (1024, 256) -- second output

    float* ws    = (float*)d_ws;
    float* cs    = ws;                       // 256   (column sums of ep)
    float* M     = ws + NY;                  // 65536 (uncentered 2nd moment)
    float* stepv = ws + NY + NY * NY;        // 1

    yhat_kernel<<<NOBS, 256, 0, stream>>>(X, W, b, yhat);
    sigmaM_kernel<<<NY, 256, 0, stream>>>(Y, yhat, M, cs);
    step_kernel<<<1, 1024, 0, stream>>>(M, cs, stepv);
    fista_mfma_kernel<<<NBLK, 256, 0, stream>>>(M, cs, yhat, stepv, z_out);
}

// Round 13
// 286.369 us; speedup vs baseline: 2.1658x; 1.0899x over previous
//
#include <hip/hip_runtime.h>
#include <math.h>

#define NOBS 1024
#define NX   128
#define NY   256
#define NIT  200
#define ROWS 4                      // rows per FISTA block
#define NBLK (NOBS / ROWS)          // 256 blocks -> 1 block/CU

typedef _Float16 f16x8 __attribute__((ext_vector_type(8)));
typedef _Float16 f16x4 __attribute__((ext_vector_type(4)));
typedef float    f32x4 __attribute__((ext_vector_type(4)));

// ---- fast 64-lane sum: 6 DPP adds, total lands in lane 63, readlane -> SGPR
template <int CTRL>
__device__ __forceinline__ float dpp_add(float x) {
    int yi = __builtin_amdgcn_update_dpp(0, __builtin_bit_cast(int, x),
                                         CTRL, 0xF, 0xF, true);
    return x + __builtin_bit_cast(float, yi);
}
__device__ __forceinline__ float dpp_sum64(float x) {
    x = dpp_add<0x111>(x);   // row_shr:1
    x = dpp_add<0x112>(x);   // row_shr:2
    x = dpp_add<0x114>(x);   // row_shr:4
    x = dpp_add<0x118>(x);   // row_shr:8
    x = dpp_add<0x142>(x);   // row_bcast:15
    x = dpp_add<0x143>(x);   // row_bcast:31
    return __builtin_bit_cast(float,
        __builtin_amdgcn_readlane(__builtin_bit_cast(int, x), 63));
}

// ---------------------------------------------------------------------------
// K1: Y_hat = X @ W^T + b ; optionally emit ephT[col][obs] f16 for MFMA-Sigma
// grid=(NOBS), block=256 (thread j -> column j)
// ---------------------------------------------------------------------------
template <bool WRITE_EPH>
__global__ __launch_bounds__(256) void yhat_kernel(const float* __restrict__ X,
                                                   const float* __restrict__ W,
                                                   const float* __restrict__ b,
                                                   const float* __restrict__ Y,
                                                   float* __restrict__ yhat,
                                                   _Float16* __restrict__ ephT) {
    __shared__ float xs[NX];
    const int i = blockIdx.x;
    const int j = threadIdx.x;
    if (j < NX) xs[j] = X[i * NX + j];
    __syncthreads();
    const float4* wr = reinterpret_cast<const float4*>(W + j * NX);
    const float4* xr = reinterpret_cast<const float4*>(xs);
    float acc = b[j];
#pragma unroll
    for (int k = 0; k < NX / 4; ++k) {
        float4 w4 = wr[k];
        float4 x4 = xr[k];
        acc += w4.x * x4.x + w4.y * x4.y + w4.z * x4.z + w4.w * x4.w;
    }
    yhat[i * NY + j] = acc;
    if constexpr (WRITE_EPH) {
        ephT[j * NOBS + i] = (_Float16)(Y[i * NY + j] - acc);
    }
}

// ---------------------------------------------------------------------------
// K2a (fast path): cs[c] = sum_k ephT[c][k]   grid=(NY), block=256, coalesced
// ---------------------------------------------------------------------------
__global__ __launch_bounds__(256) void cs_kernel(const _Float16* __restrict__ ephT,
                                                 float* __restrict__ cs) {
    const int c = blockIdx.x;
    const int t = threadIdx.x;
    f16x4 v = *reinterpret_cast<const f16x4*>(ephT + c * NOBS + t * 4);
    float s = (float)v[0] + (float)v[1] + (float)v[2] + (float)v[3];
    float wsum = dpp_sum64(s);
    __shared__ float red[4];
    if ((t & 63) == 0) red[t >> 6] = wsum;
    __syncthreads();
    if (t == 0) cs[c] = red[0] + red[1] + red[2] + red[3];
}

// ---------------------------------------------------------------------------
// K2b (fast path): M = ep^T ep / N via MFMA. grid=64 blocks x 256 thr (4 waves),
// wave computes one 16x16 tile (t = blk*4+w; c0=(t>>4)*16 rows, c1=(t&15)*16
// cols), K=1024 in 32 MFMAs. Both fragments are contiguous 16B rows of ephT.
// ---------------------------------------------------------------------------
__global__ __launch_bounds__(256) void sigma_mfma_kernel(const _Float16* __restrict__ ephT,
                                                         float* __restrict__ M) {
    const int w    = threadIdx.x >> 6;
    const int lane = threadIdx.x & 63;
    const int t    = blockIdx.x * 4 + w;
    const int c0   = (t >> 4) << 4;
    const int c1   = (t & 15) << 4;
    const int ksub = (lane >> 4) * 8;

    const _Float16* pa = ephT + (c0 + (lane & 15)) * NOBS + ksub;
    const _Float16* pb = ephT + (c1 + (lane & 15)) * NOBS + ksub;

    f32x4 acc = {0.f, 0.f, 0.f, 0.f};
#pragma unroll 8
    for (int kk = 0; kk < 32; ++kk) {
        f16x8 a = *reinterpret_cast<const f16x8*>(pa + kk * 32);
        f16x8 b = *reinterpret_cast<const f16x8*>(pb + kk * 32);
        acc = __builtin_amdgcn_mfma_f32_16x16x32_f16(a, b, acc, 0, 0, 0);
    }
    const int col  = c1 + (lane & 15);
    const int row0 = c0 + (lane >> 4) * 4;
#pragma unroll
    for (int i = 0; i < 4; ++i)
        M[(row0 + i) * NY + col] = acc[i] * (1.0f / NOBS);
}

// ---------------------------------------------------------------------------
// K2 (fallback path, scalar): M + cs from Y,yhat (r12 version)
// ---------------------------------------------------------------------------
__global__ __launch_bounds__(256) void sigmaM_kernel(const float* __restrict__ Y,
                                                     const float* __restrict__ yhat,
                                                     float* __restrict__ M,
                                                     float* __restrict__ cs) {
    const int a = blockIdx.x;
    const int j = threadIdx.x;
    __shared__ float ca[NOBS];
    for (int i = j; i < NOBS; i += 256)
        ca[i] = Y[i * NY + a] - yhat[i * NY + a];
    __syncthreads();
    float s4 = ca[j] + ca[j + 256] + ca[j + 512] + ca[j + 768];
    float wsum = dpp_sum64(s4);
    __shared__ float red[4];
    if ((j & 63) == 0) red[j >> 6] = wsum;
    __syncthreads();
    if (j == 0) cs[a] = red[0] + red[1] + red[2] + red[3];
    float s = 0.f;
#pragma unroll 4
    for (int i = 0; i < NOBS; ++i) {
        float cj = Y[i * NY + j] - yhat[i * NY + j];
        s += ca[i] * cj;
    }
    M[a * NY + j] = s * (1.0f / NOBS);
}

// ---------------------------------------------------------------------------
// K3: step = 1 / (2*||M - mu mu'||_F + 1e-8)      grid=(1), block=1024
// ---------------------------------------------------------------------------
__global__ __launch_bounds__(1024) void step_kernel(const float* __restrict__ M,
                                                    const float* __restrict__ cs,
                                                    float* __restrict__ stepv) {
    const int t = threadIdx.x;
    const float invN2 = 1.0f / ((float)NOBS * (float)NOBS);
    float s = 0.f;
    for (int idx = t; idx < NY * NY; idx += 1024) {
        const int a = idx >> 8, j = idx & 255;
        float v = M[idx] - cs[a] * cs[j] * invN2;
        s += v * v;
    }
#pragma unroll
    for (int off = 32; off; off >>= 1) s += __shfl_xor(s, off);
    __shared__ float red[16];
    if ((t & 63) == 0) red[t >> 6] = s;
    __syncthreads();
    if (t < 16) {
        float v = red[t];
#pragma unroll
        for (int off = 8; off; off >>= 1) v += __shfl_xor(v, off);
        if (t == 0) stepv[0] = 1.0f / (2.0f * sqrtf(v) + 1e-8f);
    }
}

// ---------------------------------------------------------------------------
// K4: persistent FISTA via MFMA — byte-identical to round 12 (best fista).
// ---------------------------------------------------------------------------
__global__ __launch_bounds__(256, 1) void fista_mfma_kernel(
        const float* __restrict__ M,
        const float* __restrict__ cs,
        const float* __restrict__ yhat,
        const float* __restrict__ stepv,
        float* __restrict__ zout) {
    __shared__ _Float16 zyA[16 * 256];    // A matrix, swizzled: byte ^= (row&7)<<4
    __shared__ float    gbuf[ROWS * 264]; // grad exchange, padded rows

    const int tid  = threadIdx.x;
    const int w    = tid >> 6;           // wave id = column-slice id = row id
    const int lane = tid & 63;
    const int r0   = blockIdx.x * ROWS;

    const float st    = stepv[0];
    const float st2   = 2.0f * st;
    const float invN2 = 1.0f / ((float)NOBS * (float)NOBS);

    {
        f16x8 zv = {0, 0, 0, 0, 0, 0, 0, 0};
        for (int i = tid; i < 16 * 256 / 8; i += 256)
            *reinterpret_cast<f16x8*>(zyA + i * 8) = zv;
    }
    __syncthreads();
    {
        const _Float16 u = (_Float16)(1.0f / 256.0f);
        for (int i = tid; i < ROWS * 256; i += 256)   // rows 0..3 uniform fill
            zyA[i] = u;                               // (swizzle-invariant)
    }

    // ---- preload B fragments: B[k][col] = Sigma[col][k] = M[col][k]-mu*mu ----
    const int colg = w * 64 + (lane & 15);
    const int ksub = (lane >> 4) * 8;
    f16x8 bfr[4][8];
#pragma unroll
    for (int n = 0; n < 4; ++n) {
        const int col = colg + n * 16;
        const float cfac = cs[col] * invN2;
#pragma unroll
        for (int kk = 0; kk < 8; ++kk) {
            const float* p  = M  + col * NY + kk * 32 + ksub;
            const float* pc = cs + kk * 32 + ksub;
            float4 lo = *reinterpret_cast<const float4*>(p);
            float4 hi = *reinterpret_cast<const float4*>(p + 4);
            float4 cl = *reinterpret_cast<const float4*>(pc);
            float4 ch = *reinterpret_cast<const float4*>(pc + 4);
            f16x8 bv;
            bv[0] = (_Float16)(lo.x - cfac * cl.x);
            bv[1] = (_Float16)(lo.y - cfac * cl.y);
            bv[2] = (_Float16)(lo.z - cfac * cl.z);
            bv[3] = (_Float16)(lo.w - cfac * cl.w);
            bv[4] = (_Float16)(hi.x - cfac * ch.x);
            bv[5] = (_Float16)(hi.y - cfac * ch.y);
            bv[6] = (_Float16)(hi.z - cfac * ch.z);
            bv[7] = (_Float16)(hi.w - cfac * ch.w);
            bfr[n][kk] = bv;
        }
    }

    // ---- per-wave owned row state (regs) ----
    f32x4 styh4, zy_own, zz;
    {
        const float* yp = yhat + (r0 + w) * NY + lane * 4;
        f32x4 yh = *reinterpret_cast<const f32x4*>(yp);
        styh4[0] = st * yh[0]; styh4[1] = st * yh[1];
        styh4[2] = st * yh[2]; styh4[3] = st * yh[3];
    }
    const float u0 = 1.0f / 256.0f;
    zy_own[0] = u0; zy_own[1] = u0; zy_own[2] = u0; zy_own[3] = u0;
    zz = zy_own;
    float tk = 1.0f;
    float th = 0.0f;                      // warm-started simplex threshold
    __syncthreads();

    const int arow  = lane & 15;
    const int abase = arow * 512;
    const int aswz  = (arow & 7) << 4;

    for (int it = 0; it < NIT; ++it) {
        // ---- PREFETCH all 8 A-fragments (back-to-back ds_read_b128) ----
        f16x8 af[8];
#pragma unroll
        for (int kk = 0; kk < 8; ++kk) {
            const int aoff = (kk * 64 + (lane >> 4) * 16) ^ aswz;
            af[kk] = *reinterpret_cast<const f16x8*>(
                reinterpret_cast<const char*>(zyA) + abase + aoff);
        }
        // ---- MFMA burst: 8 independent chains, 4-deep each ----
        f32x4 accA[4] = {{0,0,0,0},{0,0,0,0},{0,0,0,0},{0,0,0,0}};
        f32x4 accB[4] = {{0,0,0,0},{0,0,0,0},{0,0,0,0},{0,0,0,0}};
#pragma unroll
        for (int kk = 0; kk < 8; kk += 2) {
#pragma unroll
            for (int n = 0; n < 4; ++n) {
                accA[n] = __builtin_amdgcn_mfma_f32_16x16x32_f16(af[kk],     bfr[n][kk],
                                                                 accA[n], 0, 0, 0);
                accB[n] = __builtin_amdgcn_mfma_f32_16x16x32_f16(af[kk + 1], bfr[n][kk + 1],
                                                                 accB[n], 0, 0, 0);
            }
        }
        // ---- epilogue: pure dump of raw grad rows 0..3 ----
        if (lane < 16) {
#pragma unroll
            for (int r = 0; r < ROWS; ++r)
#pragma unroll
                for (int n = 0; n < 4; ++n)
                    gbuf[r * 264 + w * 64 + n * 16 + lane] = accA[n][r] + accB[n][r];
        }
        __syncthreads();

        // ---- projection: v from regs + one LDS read of g (row w) ----
        f32x4 g4 = *reinterpret_cast<const f32x4*>(gbuf + w * 264 + lane * 4);
        f32x4 v4;
        v4[0] = zy_own[0] - st2 * g4[0] + styh4[0];
        v4[1] = zy_own[1] - st2 * g4[1] + styh4[1];
        v4[2] = zy_own[2] - st2 * g4[2] + styh4[2];
        v4[3] = zy_own[3] - st2 * g4[3] + styh4[3];

        if (it != NIT - 1) {
            // ---- FIXED 3-trip branchless Newton (uniform across waves) ----
            float ps   = dpp_sum64(v4[0] + v4[1] + v4[2] + v4[3]);
            float th0n = (ps - 1.0f) * (1.0f / 256.0f);   // lower bound on th*
#pragma unroll
            for (int nit = 0; nit < 3; ++nit) {
                float d0 = v4[0] - th, d1 = v4[1] - th;
                float d2 = v4[2] - th, d3 = v4[3] - th;
                float sp = fmaxf(d0, 0.f) + fmaxf(d1, 0.f) +
                           fmaxf(d2, 0.f) + fmaxf(d3, 0.f);
                float s_tot = dpp_sum64(sp);
                int ci = __popcll(__ballot(d0 > 0.f)) + __popcll(__ballot(d1 > 0.f)) +
                         __popcll(__ballot(d2 > 0.f)) + __popcll(__ballot(d3 > 0.f));
                float cf   = fmaxf((float)ci, 1.0f);
                float thn  = th + (s_tot - 1.0f) * __builtin_amdgcn_rcpf(cf);
                th = (ci == 0) ? th0n : thn;               // branchless restart
            }
        } else {
            // ---- final iteration: exact solve, early exit ----
            for (int nit = 0; nit < 24; ++nit) {
                float d0 = v4[0] - th, d1 = v4[1] - th;
                float d2 = v4[2] - th, d3 = v4[3] - th;
                float sp = fmaxf(d0, 0.f) + fmaxf(d1, 0.f) +
                           fmaxf(d2, 0.f) + fmaxf(d3, 0.f);
                float s_tot = dpp_sum64(sp);
                int ci = __popcll(__ballot(d0 > 0.f)) + __popcll(__ballot(d1 > 0.f)) +
                         __popcll(__ballot(d2 > 0.f)) + __popcll(__ballot(d3 > 0.f));
                if (ci == 0) {
                    float ps = dpp_sum64(v4[0] + v4[1] + v4[2] + v4[3]);
                    th = (ps - 1.0f) * (1.0f / 256.0f);
                    continue;
                }
                if (fabsf(s_tot - 1.0f) <= 1e-6f) break;
                th += (s_tot - 1.0f) / (float)ci;
            }
        }

        f32x4 zn;
        zn[0] = fmaxf(v4[0] - th, 0.f);
        zn[1] = fmaxf(v4[1] - th, 0.f);
        zn[2] = fmaxf(v4[2] - th, 0.f);
        zn[3] = fmaxf(v4[3] - th, 0.f);

        const float tn   = 0.5f * (1.0f + sqrtf(1.0f + 4.0f * tk * tk));
        const float beta = (tk - 1.0f) / tn;
        tk = tn;
        f32x4 zyn;
        zyn[0] = zn[0] + beta * (zn[0] - zz[0]);
        zyn[1] = zn[1] + beta * (zn[1] - zz[1]);
        zyn[2] = zn[2] + beta * (zn[2] - zz[2]);
        zyn[3] = zn[3] + beta * (zn[3] - zz[3]);
        zz = zn;
        zy_own = zyn;

        // write zyn f16 -> zyA (swizzled row w)
        {
            const int off = (lane * 8) ^ ((w & 7) << 4);
            f16x4 hz;
            hz[0] = (_Float16)zyn[0]; hz[1] = (_Float16)zyn[1];
            hz[2] = (_Float16)zyn[2]; hz[3] = (_Float16)zyn[3];
            *reinterpret_cast<f16x4*>(
                reinterpret_cast<char*>(zyA) + w * 512 + off) = hz;
        }
        __syncthreads();
    }

    // ---- output: wave w writes row r0+w ----
    *reinterpret_cast<f32x4*>(zout + (r0 + w) * NY + lane * 4) = zz;
}

// ---------------------------------------------------------------------------
extern "C" void kernel_launch(void* const* d_in, const int* in_sizes, int n_in,
                              void* d_out, int out_size, void* d_ws, size_t ws_size,
                              hipStream_t stream) {
    const float* X = (const float*)d_in[0];
    const float* Y = (const float*)d_in[1];
    const float* W = (const float*)d_in[2];
    const float* b = (const float*)d_in[3];

    float* z_out = (float*)d_out;            // (1024, 256)
    float* yhat  = z_out + NOBS * NY;        // (1024, 256) -- second output

    float* ws    = (float*)d_ws;
    float* cs    = ws;                       // [0..255]      column sums of ep
    float* M     = ws + NY;                  // [256..65791]  2nd moment
    float* stepv = ws + NY + NY * NY;        // [65792]
    _Float16* ephT = (_Float16*)(ws + 65796);  // 16B-aligned, 256x1024 f16

    const size_t needed = 65796ull * 4 + (size_t)NOBS * NY * 2;
    const bool fast = (ws_size >= needed);

    if (fast) {
        yhat_kernel<true><<<NOBS, 256, 0, stream>>>(X, W, b, Y, yhat, ephT);
        cs_kernel<<<NY, 256, 0, stream>>>(ephT, cs);
        sigma_mfma_kernel<<<64, 256, 0, stream>>>(ephT, M);
    } else {
        yhat_kernel<false><<<NOBS, 256, 0, stream>>>(X, W, b, Y, yhat, nullptr);
        sigmaM_kernel<<<NY, 256, 0, stream>>>(Y, yhat, M, cs);
    }
    step_kernel<<<1, 1024, 0, stream>>>(M, cs, stepv);
    fista_mfma_kernel<<<NBLK, 256, 0, stream>>>(M, cs, yhat, stepv, z_out);
}